// Round 1
// baseline (196.782 us; speedup 1.0000x reference)
//
#include <hip/hip_runtime.h>

typedef unsigned short u16;
typedef unsigned int u32;
typedef unsigned char u8;
typedef unsigned long long u64;

#define GG   512
#define NPG  90
#define NTOT (GG*NPG)
#define NED  921600
#define FIN  90
#define HC   64
#define KP   70
#define AW   23      // packed-A words per row (23*4 = 92 >= 90)
#define AWG  (NPG*AW) // 2070 words per graph

#define SAD  92      // regA row stride (floats): 16B-aligned rows; all row reads are
                     // wave-uniform broadcasts so bank stride is irrelevant

// wf (f32 weights in ws) layout, float offsets:
#define WF_W1L 0
#define WF_W1R 5760
#define WF_W2L 11520
#define WF_W2R 15616
#define WF_B1  19712
#define WF_B2  19776
#define WF_FOLD 19840
#define WF_ZC  24320
#define WF_FLAG 24321

// k_fused LDS layout (bytes):
//  regA  [90][92] f32 : x during GEMM1, then A for the Aggs         33120
//  regB  11776 floats : W1pair [92][128] during GEMM1,
//                       then P [92][64] | P2 [92][64] halves,
//                       then r1 (low half), then h2 (low half)      47104
//  rcs/key/red/ord                                                  ~900
#define LDS_REGA 0
#define LDS_REGB 33120
#define LDS_RCS  80224
#define LDS_KEY  80592
#define LDS_RED  80960
#define LDS_ORD  80992
#define LDS_TOT  81136   // x2 blocks = 162272 <= 163840 -> 2 blocks/CU kept

__device__ __forceinline__ float bf2f(u16 u) {
    union { u32 i; float f; } v; v.i = ((u32)u) << 16; return v.f;
}
__device__ __forceinline__ float bflo(u32 u) {
    union { u32 i; float f; } v; v.i = u << 16; return v.f;
}
__device__ __forceinline__ float bfhi(u32 u) {
    union { u32 i; float f; } v; v.i = u & 0xFFFF0000u; return v.f;
}
__device__ __forceinline__ u16 f2bf(float f) {
    union { float f; u32 i; } v; v.f = f;
    u32 r = (v.i + 0x7FFFu + ((v.i >> 16) & 1u)) >> 16;
    return (u16)r;
}
__device__ __forceinline__ float ldadp(const void* p, long long i, int isf32) {
    return isf32 ? ((const float*)p)[i] : bf2f(((const u16*)p)[i]);
}

// ---- merged prep: byte-packed dense-A build + weight convert + MLP fold. (unchanged)
__global__ __launch_bounds__(256) void k_pre(
    const u32* __restrict__ xw, const int* __restrict__ ei,
    const void* W1l, const void* W1r, const void* b1,
    const void* W2l, const void* W2r, const void* b2,
    const void* Wl1, const void* bl1, const void* Wl2, const void* bl2,
    u32* __restrict__ A32, float* __restrict__ wf)
{
    __shared__ int sf;
    const int t = threadIdx.x;
    const int b = blockIdx.x;

    if (b < 900) {
        int lane = t & 63;
        u32 v = (lane < 16) ? (u32)ei[lane] : 0u;
        u64 bb = __ballot((lane & 1) && (v != 0));
        bool wide = (bb == 0ull);          // int64: odd (hi) words all zero
        int e0 = b * 1024 + t * 4;
        int s[4], d[4];
        if (wide) {
            uint4 s01 = *(const uint4*)(ei + 2 * e0);
            uint4 s23 = *(const uint4*)(ei + 2 * e0 + 4);
            uint4 d01 = *(const uint4*)(ei + 2 * (NED + e0));
            uint4 d23 = *(const uint4*)(ei + 2 * (NED + e0) + 4);
            s[0] = (int)s01.x; s[1] = (int)s01.z; s[2] = (int)s23.x; s[3] = (int)s23.z;
            d[0] = (int)d01.x; d[1] = (int)d01.z; d[2] = (int)d23.x; d[3] = (int)d23.z;
        } else {
            uint4 ss = *(const uint4*)(ei + e0);
            uint4 dd = *(const uint4*)(ei + NED + e0);
            s[0] = (int)ss.x; s[1] = (int)ss.y; s[2] = (int)ss.z; s[3] = (int)ss.w;
            d[0] = (int)dd.x; d[1] = (int)dd.y; d[2] = (int)dd.z; d[3] = (int)dd.w;
        }
        #pragma unroll
        for (int k = 0; k < 4; ++k) {
            int dk = d[k];
            if ((unsigned)dk >= NTOT) continue;
            int g = (unsigned)dk / NPG;
            int dl = dk - g * NPG;
            int ls = s[k] - g * NPG;
            if ((unsigned)ls >= NPG) continue;
            atomicAdd(&A32[(size_t)g * AWG + dl * AW + (ls >> 2)],
                      1u << (8 * (ls & 3)));
        }
        return;
    }

    if (t < 64) {
        u32 e = (xw[t] >> 7) & 0xFF;       // exponent of low-half-as-bf16
        u64 bb = __ballot(e >= 136);       // impossible for N(0,1)-scale bf16
        if (t == 0) sf = (bb != 0ull) ? 1 : 0;
    }
    __syncthreads();
    const int f32 = sf;

    if (b < 978) {
        int i = (b - 900) * 256 + t;
        if      (i < 5760)  wf[i] = ldadp(W1l, i, f32);
        else if (i < 11520) wf[i] = ldadp(W1r, i - 5760, f32);
        else if (i < 15616) wf[i] = ldadp(W2l, i - 11520, f32);
        else if (i < 19712) wf[i] = ldadp(W2r, i - 15616, f32);
        else if (i < 19776) wf[i] = ldadp(b1, i - 19712, f32);
        else if (i < 19840) wf[i] = ldadp(b2, i - 19776, f32);
        if (b == 900 && t == 0) wf[WF_FLAG] = f32 ? 1.0f : 0.0f;
    } else {
        int m = (b - 978) * 256 + t;
        if (m < 4480) {
            float s = 0.f;
            for (int j = 0; j < HC; ++j)
                s += ldadp(Wl1, (long long)m * HC + j, f32) * ldadp(Wl2, j, f32);
            wf[WF_FOLD + m] = s;
        } else if (m == 4480) {
            float s = ldadp(bl2, 0, f32);
            for (int j = 0; j < HC; ++j)
                s += ldadp(bl1, j, f32) * ldadp(Wl2, j, f32);
            wf[WF_ZC] = s;
        }
    }
}

// ---- fused pipeline, column-per-lane mapping:
//   lane  = output column c (0..63)
//   wave  = 12-row stripe (wave 7: rows 78..89; rows 78..83 duplicated with
//           wave 6 -> bitwise-identical redundant writes, uniform unroll of 12)
// All LDS reads are wave-uniform broadcasts (x/A/r1 rows, float4) or
// lane-stride-1 (P/P2/weights) -> conflict-free by construction.
__global__ __launch_bounds__(512, 4) void k_fused(
    const void* __restrict__ x, const u32* __restrict__ A32,
    const float* __restrict__ wf, void* __restrict__ dout)
{
    __shared__ __align__(16) char smem[LDS_TOT];
    float* regA  = (float*)(smem + LDS_REGA);   // [90][92]
    float* regB  = (float*)(smem + LDS_REGB);   // 11776 floats
    float* s_rcs = (float*)(smem + LDS_RCS);    // [90]
    float* s_key = (float*)(smem + LDS_KEY);    // [90]
    float* s_red = (float*)(smem + LDS_RED);    // [8]
    u16*   s_ord = (u16*)(smem + LDS_ORD);      // [72]

    const int g = blockIdx.x;
    const int t = threadIdx.x;
    const bool isf32 = (wf[WF_FLAG] > 0.5f);
    const int c = t & 63;
    const int w = __builtin_amdgcn_readfirstlane(t >> 6);
    const int r0 = (w < 7) ? w * 12 : 78;       // wave-uniform row base

    // ---- prefetch packed A into regs (held for the whole kernel) ----
    u32 abuf[5];
    const u32* Ag = A32 + (size_t)g * AWG;
    #pragma unroll
    for (int j = 0; j < 5; ++j) {
        int p = t + j * 512;
        abuf[j] = (p < AWG) ? Ag[p] : 0u;
    }

    // ---- row degrees -> rcs (exact integer sums; L2-hot behind abuf) ----
    if (t < NPG) {
        const u32* Ar = Ag + t * AW;
        u32 s = 0;
        #pragma unroll
        for (int i = 0; i < AW; ++i) {
            u32 v = Ar[i];
            s += (v & 255u) + ((v >> 8) & 255u) + ((v >> 16) & 255u) + (v >> 24);
        }
        s_rcs[t] = 1.0f / fmaxf((float)s, 1.0f);
    }

    // ---- stage x -> regA (expand bf16 to f32; single GEMM path) ----
    if (isf32) {
        const float* xg = (const float*)x + (size_t)g * 8100;
        for (int p = t; p < 8100; p += 512) {
            int r = p / NPG, cc = p - r * NPG;
            regA[r * SAD + cc] = xg[p];
        }
    } else {
        const u32* xg = (const u32*)((const u16*)x + (size_t)g * 8100);
        for (int p = t; p < 4050; p += 512) {
            int r = p / 45, cc = (p - r * 45) * 2;
            u32 v = xg[p];
            regA[r * SAD + cc]     = bflo(v);
            regA[r * SAD + cc + 1] = bfhi(v);
        }
    }
    if (t < 180) regA[(t >> 1) * SAD + 90 + (t & 1)] = 0.f;   // x pad cols -> exact +0

    // ---- stage W1 paired [92][128]: (Wl,Wr) adjacent per (k,c); rows 90,91 zero ----
    for (int idx = t; idx < 92 * 64; idx += 512) {
        int k = idx >> 6, cc = idx & 63;
        float wl = 0.f, wr = 0.f;
        if (k < FIN) { wl = wf[WF_W1L + k * HC + cc]; wr = wf[WF_W1R + k * HC + cc]; }
        *(float2*)(regB + k * 128 + 2 * cc) = make_float2(wl, wr);
    }
    __syncthreads();  // B0

    // ---- GEMM1: P = x@W1l, Q = x@W1r + b1 ; fmaf chains in ascending k ----
    float accP[12], accQ[12];
    {
        float bv = wf[WF_B1 + c];
        #pragma unroll
        for (int r = 0; r < 12; ++r) { accP[r] = 0.f; accQ[r] = bv; }
    }
    {
        const float* Wp = regB + 2 * c;
        const float* Xp = regA + r0 * SAD;
        for (int k0 = 0; k0 < 23; ++k0) {
            float2 w0 = *(const float2*)(Wp + k0 * 512);
            float2 w1 = *(const float2*)(Wp + k0 * 512 + 128);
            float2 w2 = *(const float2*)(Wp + k0 * 512 + 256);
            float2 w3 = *(const float2*)(Wp + k0 * 512 + 384);
            #pragma unroll
            for (int r = 0; r < 12; ++r) {
                float4 xv = *(const float4*)(Xp + r * SAD + k0 * 4);  // broadcast
                accP[r] = fmaf(xv.x, w0.x, accP[r]);
                accQ[r] = fmaf(xv.x, w0.y, accQ[r]);
                accP[r] = fmaf(xv.y, w1.x, accP[r]);
                accQ[r] = fmaf(xv.y, w1.y, accQ[r]);
                accP[r] = fmaf(xv.z, w2.x, accP[r]);
                accQ[r] = fmaf(xv.z, w2.y, accQ[r]);
                accP[r] = fmaf(xv.w, w3.x, accP[r]);
                accQ[r] = fmaf(xv.w, w3.y, accQ[r]);
            }
        }
    }
    __syncthreads();  // B1: x and W1 reads done; regA/regB reusable

    // ---- write P [92][64] (low half of regB); zero pad rows of P and P2;
    //      unpack A bytes -> regA f32 [90][92] (pad bytes 90,91 are hw-zero) ----
    #pragma unroll
    for (int r = 0; r < 12; ++r) regB[(r0 + r) * HC + c] = accP[r];
    if (t < 128) {
        regB[90 * HC + t]        = 0.f;   // P rows 90,91
        regB[5888 + 90 * HC + t] = 0.f;   // P2 rows 90,91
    }
    #pragma unroll
    for (int j = 0; j < 5; ++j) {
        int p = t + j * 512;
        if (p < AWG) {
            int r = p / AW, wc = p - r * AW;
            u32 v = abuf[j];
            *(float4*)(regA + r * SAD + wc * 4) = make_float4(
                (float)(v & 255u), (float)((v >> 8) & 255u),
                (float)((v >> 16) & 255u), (float)(v >> 24));
        }
    }
    __syncthreads();  // B2: A and P complete

    // ---- Agg1: h1 = rc*(A@P) + Q ; store x_train; keep relu in regs ----
    float h1[12];
    {
        float acc[12];
        #pragma unroll
        for (int r = 0; r < 12; ++r) acc[r] = 0.f;
        const float* Ap = regA + r0 * SAD;
        const float* Pp = regB + c;
        for (int k0 = 0; k0 < 23; ++k0) {
            float p0 = Pp[(4 * k0 + 0) * HC];
            float p1 = Pp[(4 * k0 + 1) * HC];
            float p2 = Pp[(4 * k0 + 2) * HC];
            float p3 = Pp[(4 * k0 + 3) * HC];
            #pragma unroll
            for (int r = 0; r < 12; ++r) {
                float4 av = *(const float4*)(Ap + r * SAD + k0 * 4);  // broadcast
                acc[r] = fmaf(av.x, p0, acc[r]);
                acc[r] = fmaf(av.y, p1, acc[r]);
                acc[r] = fmaf(av.z, p2, acc[r]);
                acc[r] = fmaf(av.w, p3, acc[r]);
            }
        }
        if (isf32) {
            #pragma unroll
            for (int r = 0; r < 12; ++r) {
                float h = fmaf(s_rcs[r0 + r], acc[r], accQ[r]);
                ((float*)dout)[512 + (size_t)(g * NPG + r0 + r) * HC + c] = h;
                h1[r] = fmaxf(h, 0.f);
            }
        } else {
            #pragma unroll
            for (int r = 0; r < 12; ++r) {
                float h = fmaf(s_rcs[r0 + r], acc[r], accQ[r]);
                ((u16*)dout)[512 + (size_t)(g * NPG + r0 + r) * HC + c] = f2bf(h);
                h1[r] = fmaxf(h, 0.f);
            }
        }
    }
    __syncthreads();  // B3: P reads done, low half of regB reusable

    // ---- r1 -> LDS (own-wave rows), GEMM2, P2 -> high half: NO internal barriers
    //      (every wave reads only r1 rows it wrote itself; P2 half is write-only) ----
    #pragma unroll
    for (int r = 0; r < 12; ++r) regB[(r0 + r) * HC + c] = h1[r];
    float accQ2[12];
    {
        float bv = wf[WF_B2 + c];
        #pragma unroll
        for (int r = 0; r < 12; ++r) { accP[r] = 0.f; accQ2[r] = bv; }
        const float* WL = wf + WF_W2L + c;   // global, L1-resident (32 KB)
        const float* WR = wf + WF_W2R + c;
        const float* Rp = regB + r0 * HC;
        for (int k0 = 0; k0 < 16; ++k0) {
            float wl0 = WL[(4 * k0 + 0) * HC], wr0 = WR[(4 * k0 + 0) * HC];
            float wl1 = WL[(4 * k0 + 1) * HC], wr1 = WR[(4 * k0 + 1) * HC];
            float wl2 = WL[(4 * k0 + 2) * HC], wr2 = WR[(4 * k0 + 2) * HC];
            float wl3 = WL[(4 * k0 + 3) * HC], wr3 = WR[(4 * k0 + 3) * HC];
            #pragma unroll
            for (int r = 0; r < 12; ++r) {
                float4 rv = *(const float4*)(Rp + r * HC + k0 * 4);   // broadcast
                accP[r]  = fmaf(rv.x, wl0, accP[r]);
                accQ2[r] = fmaf(rv.x, wr0, accQ2[r]);
                accP[r]  = fmaf(rv.y, wl1, accP[r]);
                accQ2[r] = fmaf(rv.y, wr1, accQ2[r]);
                accP[r]  = fmaf(rv.z, wl2, accP[r]);
                accQ2[r] = fmaf(rv.z, wr2, accQ2[r]);
                accP[r]  = fmaf(rv.w, wl3, accP[r]);
                accQ2[r] = fmaf(rv.w, wr3, accQ2[r]);
            }
        }
    }
    {
        float* P2 = regB + 5888;
        #pragma unroll
        for (int r = 0; r < 12; ++r) P2[(r0 + r) * HC + c] = accP[r];
    }
    __syncthreads();  // B4: P2 complete (A in regA untouched since B2)

    // ---- Agg2: h2 = rc*(A@P2) + Q2 ; key = col 63 ----
    float h2v[12];
    {
        float acc[12];
        #pragma unroll
        for (int r = 0; r < 12; ++r) acc[r] = 0.f;
        const float* Ap = regA + r0 * SAD;
        const float* Pp = regB + 5888 + c;
        for (int k0 = 0; k0 < 23; ++k0) {
            float p0 = Pp[(4 * k0 + 0) * HC];
            float p1 = Pp[(4 * k0 + 1) * HC];
            float p2 = Pp[(4 * k0 + 2) * HC];
            float p3 = Pp[(4 * k0 + 3) * HC];
            #pragma unroll
            for (int r = 0; r < 12; ++r) {
                float4 av = *(const float4*)(Ap + r * SAD + k0 * 4);  // broadcast
                acc[r] = fmaf(av.x, p0, acc[r]);
                acc[r] = fmaf(av.y, p1, acc[r]);
                acc[r] = fmaf(av.z, p2, acc[r]);
                acc[r] = fmaf(av.w, p3, acc[r]);
            }
        }
        #pragma unroll
        for (int r = 0; r < 12; ++r)
            h2v[r] = fmaf(s_rcs[r0 + r], acc[r], accQ2[r]);
        if (c == 63) {
            #pragma unroll
            for (int r = 0; r < 12; ++r) s_key[r0 + r] = h2v[r];
        }
    }
    __syncthreads();  // B5: P2 reads done; s_key complete

    // ---- h2 -> low half of regB; stable descending rank ----
    #pragma unroll
    for (int r = 0; r < 12; ++r) regB[(r0 + r) * HC + c] = h2v[r];
    if (t < NPG) {
        float my = s_key[t];
        int rk = 0;
        for (int m2 = 0; m2 < NPG; ++m2) {
            float km = s_key[m2];
            rk += (km > my) || (km == my && m2 < t);
        }
        if (rk < KP) s_ord[rk] = (u16)t;
    }
    __syncthreads();  // B6: h2 + s_ord ready

    // ---- folded MLP: z = sum p*W_fold + zc ; sigmoid ----
    float zp = 0.f;
    for (int p = t; p < KP * HC; p += 512) {
        int i = p >> 6, cc = p & 63;
        int nn = s_ord[i];
        zp += regB[nn * HC + cc] * wf[WF_FOLD + p];
    }
    #pragma unroll
    for (int off = 32; off > 0; off >>= 1) zp += __shfl_down(zp, off);
    if ((t & 63) == 0) s_red[t >> 6] = zp;
    __syncthreads();  // B7
    if (t == 0) {
        float z = wf[WF_ZC];
        #pragma unroll
        for (int i = 0; i < 8; ++i) z += s_red[i];
        float sg = 1.0f / (1.0f + expf(-z));
        if (isf32) ((float*)dout)[g] = sg;
        else       ((u16*)dout)[g]   = f2bf(sg);
    }
}

extern "C" void kernel_launch(void* const* d_in, const int* in_sizes, int n_in,
                              void* d_out, int out_size, void* d_ws, size_t ws_size,
                              hipStream_t stream) {
    const void* x   = d_in[0];
    const int*  ei  = (const int*)d_in[1];
    const void* W1l = d_in[3];
    const void* W1r = d_in[4];
    const void* b1  = d_in[5];
    const void* W2l = d_in[6];
    const void* W2r = d_in[7];
    const void* b2  = d_in[8];
    const void* Wl1 = d_in[9];
    const void* bl1 = d_in[10];
    const void* Wl2 = d_in[11];
    const void* bl2 = d_in[12];

    char* ws    = (char*)d_ws;
    u32*  A32   = (u32*)ws;                      // 4,239,360 B (512 x 2070 u32)
    float* wf   = (float*)(ws + 4239360);        // 97,288 B (total ~4.34 MB)

    hipMemsetAsync(A32, 0, 4239360, stream);
    k_pre<<<996, 256, 0, stream>>>((const u32*)x, ei, W1l, W1r, b1, W2l, W2r, b2,
                                   Wl1, bl1, Wl2, bl2, A32, wf);
    k_fused<<<GG, 512, 0, stream>>>(x, A32, wf, d_out);
}

// Round 2
// 186.100 us; speedup vs baseline: 1.0574x; 1.0574x over previous
//
#include <hip/hip_runtime.h>

typedef unsigned short u16;
typedef unsigned int u32;
typedef unsigned char u8;
typedef unsigned long long u64;

#define GG   512
#define NPG  90
#define NTOT (GG*NPG)
#define NED  921600
#define FIN  90
#define HC   64
#define KP   70
#define AW   23      // packed-A words per row (23*4 = 92 >= 90)
#define AWG  (NPG*AW) // 2070 words per graph

#define SAD  92   // x stride (floats): 16B-aligned rows -> ds_read_b128; 23l mod 32 bijective
#define SP   68   // P/r1/P2/h2 stride: float4 rows 16B-aligned; 17l mod 32 bijective
#define APW  25   // packed-A LDS stride (words): 25l mod 32 bijective -> conflict-free b32

// wf (f32 weights in ws) layout, float offsets:
#define WF_W1L 0
#define WF_W1R 5760
#define WF_W2L 11520
#define WF_W2R 15616
#define WF_B1  19712
#define WF_B2  19776
#define WF_FOLD 19840
#define WF_ZC  24320
#define WF_FLAG 24321

__device__ __forceinline__ float bf2f(u16 u) {
    union { u32 i; float f; } v; v.i = ((u32)u) << 16; return v.f;
}
__device__ __forceinline__ float bflo(u32 u) {
    union { u32 i; float f; } v; v.i = u << 16; return v.f;
}
__device__ __forceinline__ float bfhi(u32 u) {
    union { u32 i; float f; } v; v.i = u & 0xFFFF0000u; return v.f;
}
__device__ __forceinline__ u16 f2bf(float f) {
    union { float f; u32 i; } v; v.f = f;
    u32 r = (v.i + 0x7FFFu + ((v.i >> 16) & 1u)) >> 16;
    return (u16)r;
}
__device__ __forceinline__ float ldadp(const void* p, long long i, int isf32) {
    return isf32 ? ((const float*)p)[i] : bf2f(((const u16*)p)[i]);
}

// ---- merged prep: byte-packed dense-A build + weight convert + MLP fold. (unchanged)
__global__ __launch_bounds__(256) void k_pre(
    const u32* __restrict__ xw, const int* __restrict__ ei,
    const void* W1l, const void* W1r, const void* b1,
    const void* W2l, const void* W2r, const void* b2,
    const void* Wl1, const void* bl1, const void* Wl2, const void* bl2,
    u32* __restrict__ A32, float* __restrict__ wf)
{
    __shared__ int sf;
    const int t = threadIdx.x;
    const int b = blockIdx.x;

    if (b < 900) {
        int lane = t & 63;
        u32 v = (lane < 16) ? (u32)ei[lane] : 0u;
        u64 bb = __ballot((lane & 1) && (v != 0));
        bool wide = (bb == 0ull);          // int64: odd (hi) words all zero
        int e0 = b * 1024 + t * 4;
        int s[4], d[4];
        if (wide) {
            uint4 s01 = *(const uint4*)(ei + 2 * e0);
            uint4 s23 = *(const uint4*)(ei + 2 * e0 + 4);
            uint4 d01 = *(const uint4*)(ei + 2 * (NED + e0));
            uint4 d23 = *(const uint4*)(ei + 2 * (NED + e0) + 4);
            s[0] = (int)s01.x; s[1] = (int)s01.z; s[2] = (int)s23.x; s[3] = (int)s23.z;
            d[0] = (int)d01.x; d[1] = (int)d01.z; d[2] = (int)d23.x; d[3] = (int)d23.z;
        } else {
            uint4 ss = *(const uint4*)(ei + e0);
            uint4 dd = *(const uint4*)(ei + NED + e0);
            s[0] = (int)ss.x; s[1] = (int)ss.y; s[2] = (int)ss.z; s[3] = (int)ss.w;
            d[0] = (int)dd.x; d[1] = (int)dd.y; d[2] = (int)dd.z; d[3] = (int)dd.w;
        }
        #pragma unroll
        for (int k = 0; k < 4; ++k) {
            int dk = d[k];
            if ((unsigned)dk >= NTOT) continue;
            int g = (unsigned)dk / NPG;
            int dl = dk - g * NPG;
            int ls = s[k] - g * NPG;
            if ((unsigned)ls >= NPG) continue;
            atomicAdd(&A32[(size_t)g * AWG + dl * AW + (ls >> 2)],
                      1u << (8 * (ls & 3)));
        }
        return;
    }

    if (t < 64) {
        u32 e = (xw[t] >> 7) & 0xFF;       // exponent of low-half-as-bf16
        u64 bb = __ballot(e >= 136);       // impossible for N(0,1)-scale bf16
        if (t == 0) sf = (bb != 0ull) ? 1 : 0;
    }
    __syncthreads();
    const int f32 = sf;

    if (b < 978) {
        int i = (b - 900) * 256 + t;
        if      (i < 5760)  wf[i] = ldadp(W1l, i, f32);
        else if (i < 11520) wf[i] = ldadp(W1r, i - 5760, f32);
        else if (i < 15616) wf[i] = ldadp(W2l, i - 11520, f32);
        else if (i < 19712) wf[i] = ldadp(W2r, i - 15616, f32);
        else if (i < 19776) wf[i] = ldadp(b1, i - 19712, f32);
        else if (i < 19840) wf[i] = ldadp(b2, i - 19776, f32);
        if (b == 900 && t == 0) wf[WF_FLAG] = f32 ? 1.0f : 0.0f;
    } else {
        int m = (b - 978) * 256 + t;
        if (m < 4480) {
            float s = 0.f;
            for (int j = 0; j < HC; ++j)
                s += ldadp(Wl1, (long long)m * HC + j, f32) * ldadp(Wl2, j, f32);
            wf[WF_FOLD + m] = s;
        } else if (m == 4480) {
            float s = ldadp(bl2, 0, f32);
            for (int j = 0; j < HC; ++j)
                s += ldadp(bl1, j, f32) * ldadp(Wl2, j, f32);
            wf[WF_ZC] = s;
        }
    }
}

// ---- fused pipeline: round-0 mapping (8 waves x 8-col slab, lane = rows l, l+64)
// with LDS-instruction reduction: b128 x/r1 reads, byte-packed A reads.
// LDS regions (bytes):
//   As   [90][92] f32  @0      33120  (x only; pad cols 90,91 zeroed)
//   R1   [90][68] f32  @33120  24480  (P -> r1 -> P2 -> h2, sequential reuse)
//   Apk  [90][25] u32  @57600   9000  (packed A bytes, lives whole kernel)
//   key/red/ord        @66600   ~540
__global__ __launch_bounds__(512, 4) void k_fused(
    const void* __restrict__ x, const u32* __restrict__ A32,
    const float* __restrict__ wf, void* __restrict__ dout)
{
    __shared__ __align__(16) char smem[67136];
    float* As    = (float*)smem;
    float* R1    = (float*)(smem + 33120);
    u32*   Apk   = (u32*)(smem + 57600);
    float* s_key = (float*)(smem + 66600);
    float* s_red = (float*)(smem + 66960);
    u16*   s_ord = (u16*)(smem + 66992);

    const int g = blockIdx.x;
    const int t = threadIdx.x;
    const bool isf32 = (wf[WF_FLAG] > 0.5f);

    const int l = t & 63;
    const int w = __builtin_amdgcn_readfirstlane(t >> 6);  // wave id, SGPR
    const int jb = w * 8;                                   // wave-uniform slab
    const int row0 = l;
    const bool has2 = (l < NPG - 64);
    const int row1 = has2 ? l + 64 : l;

    // ---- load packed A and store directly to LDS (no unpack pass) ----
    u32 abuf[5];
    {
        const u32* Ag = A32 + (size_t)g * AWG;
        #pragma unroll
        for (int j = 0; j < 5; ++j) {
            int p = t + j * 512;
            abuf[j] = (p < AWG) ? Ag[p] : 0u;
        }
    }

    // ---- stage x -> As (expand bf16 to f32; single GEMM path) ----
    if (isf32) {
        const float* xg = (const float*)x + (size_t)g * 8100;
        for (int p = t; p < 8100; p += 512) {
            int r = p / NPG, c = p - r * NPG;
            As[r * SAD + c] = xg[p];
        }
    } else {
        const u32* xg = (const u32*)((const u16*)x + (size_t)g * 8100);
        for (int p = t; p < 4050; p += 512) {
            int r = p / 45, c = (p - r * 45) * 2;
            u32 v = xg[p];
            As[r * SAD + c]     = bflo(v);
            As[r * SAD + c + 1] = bfhi(v);
        }
    }
    if (t < 180) As[(t >> 1) * SAD + 90 + (t & 1)] = 0.f;  // pad cols -> exact +0
    #pragma unroll
    for (int j = 0; j < 5; ++j) {
        int p = t + j * 512;
        if (p < AWG) {
            int r = p / AW, wc = p - r * AW;
            Apk[r * APW + wc] = abuf[j];
        }
    }
    __syncthreads();  // B0: x + Apk staged

    // ---- GEMM1: P = x@W1l, Q = x@W1r + b1 ; weights wave-uniform (s_load) ----
    float accP[2][8], accQ[2][8];
    {
        const float* bb = wf + WF_B1 + jb;
        #pragma unroll
        for (int j = 0; j < 8; ++j) {
            float bv = bb[j];
            accP[0][j] = 0.f; accP[1][j] = 0.f;
            accQ[0][j] = bv;  accQ[1][j] = bv;
        }
    }
    {
        const float* WL = wf + WF_W1L + jb;
        const float* WR = wf + WF_W1R + jb;
        const float* X0 = As + row0 * SAD;
        const float* X1 = As + row1 * SAD;
        for (int k0 = 0; k0 < 23; ++k0) {       // k=90,91: x=0 -> exact +0 (w reads in-bounds of wf)
            float4 q0 = *(const float4*)(X0 + 4 * k0);
            float4 q1 = *(const float4*)(X1 + 4 * k0);
            float xa0[4] = {q0.x, q0.y, q0.z, q0.w};
            float xa1[4] = {q1.x, q1.y, q1.z, q1.w};
            #pragma unroll
            for (int jj = 0; jj < 4; ++jj) {
                int k = 4 * k0 + jj;
                float wl[8], wr[8];
                #pragma unroll
                for (int j = 0; j < 8; ++j) { wl[j] = WL[k * HC + j]; wr[j] = WR[k * HC + j]; }
                #pragma unroll
                for (int j = 0; j < 8; ++j) {
                    accP[0][j] += xa0[jj] * wl[j]; accQ[0][j] += xa0[jj] * wr[j];
                    accP[1][j] += xa1[jj] * wl[j]; accQ[1][j] += xa1[jj] * wr[j];
                }
            }
        }
    }
    __syncthreads();  // B1: x reads done, R1 region writable

    // ---- write P (float4 pairs) ----
    *(float4*)(R1 + row0 * SP + jb)     = make_float4(accP[0][0], accP[0][1], accP[0][2], accP[0][3]);
    *(float4*)(R1 + row0 * SP + jb + 4) = make_float4(accP[0][4], accP[0][5], accP[0][6], accP[0][7]);
    if (has2) {
        *(float4*)(R1 + row1 * SP + jb)     = make_float4(accP[1][0], accP[1][1], accP[1][2], accP[1][3]);
        *(float4*)(R1 + row1 * SP + jb + 4) = make_float4(accP[1][4], accP[1][5], accP[1][6], accP[1][7]);
    }
    __syncthreads();  // B2: P complete

    // ---- Agg1: h1 = rc*(A@P) + Q ; A from packed bytes; rc from in-loop sum ----
    float r1v[2][8];
    float rc0, rc1;
    {
        float acc[2][8];
        float asum0 = 0.f, asum1 = 0.f;
        #pragma unroll
        for (int i = 0; i < 2; ++i)
            #pragma unroll
            for (int j = 0; j < 8; ++j) acc[i][j] = 0.f;
        const u32* A0 = Apk + row0 * APW;
        const u32* A1 = Apk + row1 * APW;
        for (int k0 = 0; k0 < 22; ++k0) {
            u32 w0 = A0[k0], w1 = A1[k0];
            #pragma unroll
            for (int jj = 0; jj < 4; ++jj) {
                int k = 4 * k0 + jj;
                float4 p0 = *(const float4*)(R1 + k * SP + jb);     // broadcast
                float4 p1 = *(const float4*)(R1 + k * SP + jb + 4);
                float pv[8] = {p0.x,p0.y,p0.z,p0.w,p1.x,p1.y,p1.z,p1.w};
                float a0 = (float)((w0 >> (8 * jj)) & 255u);
                float a1 = (float)((w1 >> (8 * jj)) & 255u);
                asum0 += a0; asum1 += a1;
                #pragma unroll
                for (int j = 0; j < 8; ++j) {
                    acc[0][j] += a0 * pv[j];
                    acc[1][j] += a1 * pv[j];
                }
            }
        }
        {   // tail k = 88, 89 (P rows 90,91 do not exist -> never read)
            u32 w0 = A0[22], w1 = A1[22];
            #pragma unroll
            for (int jj = 0; jj < 2; ++jj) {
                int k = 88 + jj;
                float4 p0 = *(const float4*)(R1 + k * SP + jb);
                float4 p1 = *(const float4*)(R1 + k * SP + jb + 4);
                float pv[8] = {p0.x,p0.y,p0.z,p0.w,p1.x,p1.y,p1.z,p1.w};
                float a0 = (float)((w0 >> (8 * jj)) & 255u);
                float a1 = (float)((w1 >> (8 * jj)) & 255u);
                asum0 += a0; asum1 += a1;
                #pragma unroll
                for (int j = 0; j < 8; ++j) {
                    acc[0][j] += a0 * pv[j];
                    acc[1][j] += a1 * pv[j];
                }
            }
        }
        rc0 = 1.0f / fmaxf(asum0, 1.0f);
        rc1 = 1.0f / fmaxf(asum1, 1.0f);
        #pragma unroll
        for (int i = 0; i < 2; ++i) {
            if (i == 0 || has2) {
                int n = i ? row1 : row0;
                float rc = i ? rc1 : rc0;
                float h[8];
                #pragma unroll
                for (int j = 0; j < 8; ++j) h[j] = fmaf(rc, acc[i][j], accQ[i][j]);
                size_t base = 512 + (size_t)(g * NPG + n) * HC + jb;
                if (isf32) {
                    *(float4*)((float*)dout + base)     = make_float4(h[0],h[1],h[2],h[3]);
                    *(float4*)((float*)dout + base + 4) = make_float4(h[4],h[5],h[6],h[7]);
                } else {
                    uint4 pk;
                    pk.x = (u32)f2bf(h[0]) | ((u32)f2bf(h[1]) << 16);
                    pk.y = (u32)f2bf(h[2]) | ((u32)f2bf(h[3]) << 16);
                    pk.z = (u32)f2bf(h[4]) | ((u32)f2bf(h[5]) << 16);
                    pk.w = (u32)f2bf(h[6]) | ((u32)f2bf(h[7]) << 16);
                    *(uint4*)((u16*)dout + base) = pk;
                }
                #pragma unroll
                for (int j = 0; j < 8; ++j) r1v[i][j] = fmaxf(h[j], 0.f);
            }
        }
    }
    __syncthreads();  // B3: P reads done
    *(float4*)(R1 + row0 * SP + jb)     = make_float4(r1v[0][0], r1v[0][1], r1v[0][2], r1v[0][3]);
    *(float4*)(R1 + row0 * SP + jb + 4) = make_float4(r1v[0][4], r1v[0][5], r1v[0][6], r1v[0][7]);
    if (has2) {
        *(float4*)(R1 + row1 * SP + jb)     = make_float4(r1v[1][0], r1v[1][1], r1v[1][2], r1v[1][3]);
        *(float4*)(R1 + row1 * SP + jb + 4) = make_float4(r1v[1][4], r1v[1][5], r1v[1][6], r1v[1][7]);
    }
    __syncthreads();  // B4: r1 complete

    // ---- GEMM2: P2 = r1@W2l, Q2 = r1@W2r + b2 ; b128 r1 reads ----
    {
        const float* bb = wf + WF_B2 + jb;
        #pragma unroll
        for (int j = 0; j < 8; ++j) {
            float bv = bb[j];
            accP[0][j] = 0.f; accP[1][j] = 0.f;
            accQ[0][j] = bv;  accQ[1][j] = bv;
        }
    }
    {
        const float* WL = wf + WF_W2L + jb;
        const float* WR = wf + WF_W2R + jb;
        const float* V0 = R1 + row0 * SP;
        const float* V1 = R1 + row1 * SP;
        for (int k0 = 0; k0 < 16; ++k0) {
            float4 q0 = *(const float4*)(V0 + 4 * k0);
            float4 q1 = *(const float4*)(V1 + 4 * k0);
            float va0[4] = {q0.x, q0.y, q0.z, q0.w};
            float va1[4] = {q1.x, q1.y, q1.z, q1.w};
            #pragma unroll
            for (int jj = 0; jj < 4; ++jj) {
                int k = 4 * k0 + jj;
                float wl[8], wr[8];
                #pragma unroll
                for (int j = 0; j < 8; ++j) { wl[j] = WL[k * HC + j]; wr[j] = WR[k * HC + j]; }
                #pragma unroll
                for (int j = 0; j < 8; ++j) {
                    accP[0][j] += va0[jj] * wl[j]; accQ[0][j] += va0[jj] * wr[j];
                    accP[1][j] += va1[jj] * wl[j]; accQ[1][j] += va1[jj] * wr[j];
                }
            }
        }
    }
    __syncthreads();  // B5: r1 reads done
    *(float4*)(R1 + row0 * SP + jb)     = make_float4(accP[0][0], accP[0][1], accP[0][2], accP[0][3]);
    *(float4*)(R1 + row0 * SP + jb + 4) = make_float4(accP[0][4], accP[0][5], accP[0][6], accP[0][7]);
    if (has2) {
        *(float4*)(R1 + row1 * SP + jb)     = make_float4(accP[1][0], accP[1][1], accP[1][2], accP[1][3]);
        *(float4*)(R1 + row1 * SP + jb + 4) = make_float4(accP[1][4], accP[1][5], accP[1][6], accP[1][7]);
    }
    __syncthreads();  // B6: P2 complete

    // ---- Agg2: h2 = rc*(A@P2) + Q2 ; key = col 63 ----
    float h2v[2][8];
    {
        float acc[2][8];
        #pragma unroll
        for (int i = 0; i < 2; ++i)
            #pragma unroll
            for (int j = 0; j < 8; ++j) acc[i][j] = 0.f;
        const u32* A0 = Apk + row0 * APW;
        const u32* A1 = Apk + row1 * APW;
        for (int k0 = 0; k0 < 22; ++k0) {
            u32 w0 = A0[k0], w1 = A1[k0];
            #pragma unroll
            for (int jj = 0; jj < 4; ++jj) {
                int k = 4 * k0 + jj;
                float4 p0 = *(const float4*)(R1 + k * SP + jb);
                float4 p1 = *(const float4*)(R1 + k * SP + jb + 4);
                float pv[8] = {p0.x,p0.y,p0.z,p0.w,p1.x,p1.y,p1.z,p1.w};
                float a0 = (float)((w0 >> (8 * jj)) & 255u);
                float a1 = (float)((w1 >> (8 * jj)) & 255u);
                #pragma unroll
                for (int j = 0; j < 8; ++j) {
                    acc[0][j] += a0 * pv[j];
                    acc[1][j] += a1 * pv[j];
                }
            }
        }
        {   // tail k = 88, 89
            u32 w0 = A0[22], w1 = A1[22];
            #pragma unroll
            for (int jj = 0; jj < 2; ++jj) {
                int k = 88 + jj;
                float4 p0 = *(const float4*)(R1 + k * SP + jb);
                float4 p1 = *(const float4*)(R1 + k * SP + jb + 4);
                float pv[8] = {p0.x,p0.y,p0.z,p0.w,p1.x,p1.y,p1.z,p1.w};
                float a0 = (float)((w0 >> (8 * jj)) & 255u);
                float a1 = (float)((w1 >> (8 * jj)) & 255u);
                #pragma unroll
                for (int j = 0; j < 8; ++j) {
                    acc[0][j] += a0 * pv[j];
                    acc[1][j] += a1 * pv[j];
                }
            }
        }
        #pragma unroll
        for (int i = 0; i < 2; ++i) {
            if (i == 0 || has2) {
                int n = i ? row1 : row0;
                float rc = i ? rc1 : rc0;
                #pragma unroll
                for (int j = 0; j < 8; ++j)
                    h2v[i][j] = fmaf(rc, acc[i][j], accQ[i][j]);
                if (w == 7) s_key[n] = h2v[i][7];
            }
        }
    }
    __syncthreads();  // B7: P2 reads done; s_key complete
    *(float4*)(R1 + row0 * SP + jb)     = make_float4(h2v[0][0], h2v[0][1], h2v[0][2], h2v[0][3]);
    *(float4*)(R1 + row0 * SP + jb + 4) = make_float4(h2v[0][4], h2v[0][5], h2v[0][6], h2v[0][7]);
    if (has2) {
        *(float4*)(R1 + row1 * SP + jb)     = make_float4(h2v[1][0], h2v[1][1], h2v[1][2], h2v[1][3]);
        *(float4*)(R1 + row1 * SP + jb + 4) = make_float4(h2v[1][4], h2v[1][5], h2v[1][6], h2v[1][7]);
    }
    // stable descending rank (== stable argsort(-key))
    if (t < NPG) {
        float my = s_key[t];
        int r = 0;
        for (int m2 = 0; m2 < NPG; ++m2) {
            float km = s_key[m2];
            r += (km > my) || (km == my && m2 < t);
        }
        if (r < KP) s_ord[r] = (u16)t;
    }
    __syncthreads();  // B8

    // ---- folded MLP: z = sum p*W_fold + zc ; sigmoid ----
    float zp = 0.f;
    for (int p = t; p < KP * HC; p += 512) {
        int i = p >> 6, c = p & 63;
        int nn = s_ord[i];
        zp += R1[nn * SP + c] * wf[WF_FOLD + p];
    }
    #pragma unroll
    for (int off = 32; off > 0; off >>= 1) zp += __shfl_down(zp, off);
    if ((t & 63) == 0) s_red[t >> 6] = zp;
    __syncthreads();  // B9
    if (t == 0) {
        float z = wf[WF_ZC];
        #pragma unroll
        for (int i = 0; i < 8; ++i) z += s_red[i];
        float sg = 1.0f / (1.0f + expf(-z));
        if (isf32) ((float*)dout)[g] = sg;
        else       ((u16*)dout)[g]   = f2bf(sg);
    }
}

extern "C" void kernel_launch(void* const* d_in, const int* in_sizes, int n_in,
                              void* d_out, int out_size, void* d_ws, size_t ws_size,
                              hipStream_t stream) {
    const void* x   = d_in[0];
    const int*  ei  = (const int*)d_in[1];
    const void* W1l = d_in[3];
    const void* W1r = d_in[4];
    const void* b1  = d_in[5];
    const void* W2l = d_in[6];
    const void* W2r = d_in[7];
    const void* b2  = d_in[8];
    const void* Wl1 = d_in[9];
    const void* bl1 = d_in[10];
    const void* Wl2 = d_in[11];
    const void* bl2 = d_in[12];

    char* ws    = (char*)d_ws;
    u32*  A32   = (u32*)ws;                      // 4,239,360 B (512 x 2070 u32)
    float* wf   = (float*)(ws + 4239360);        // 97,288 B (total ~4.34 MB)

    hipMemsetAsync(A32, 0, 4239360, stream);
    k_pre<<<996, 256, 0, stream>>>((const u32*)x, ei, W1l, W1r, b1, W2l, W2r, b2,
                                   Wl1, bl1, Wl2, bl2, A32, wf);
    k_fused<<<GG, 512, 0, stream>>>(x, A32, wf, d_out);
}